// Round 2
// baseline (253.653 us; speedup 1.0000x reference)
//
#include <hip/hip_runtime.h>
#include <cstdint>

typedef __attribute__((ext_vector_type(8))) short bf16x8_t;
typedef __attribute__((ext_vector_type(4))) float f32x4_t;

#define T_SEQ 2048
#define NHEAD 16
#define CDIM  1024

__device__ __forceinline__ unsigned short f2bf(float f) {
  union { float f; unsigned u; } v; v.f = f;
  unsigned r = v.u + 0x7FFFu + ((v.u >> 16) & 1u);
  return (unsigned short)(r >> 16);
}

__device__ __forceinline__ float fast_exp2(float x) {
#if __has_builtin(__builtin_amdgcn_exp2f)
  return __builtin_amdgcn_exp2f(x);
#else
  return __expf(x * 0.6931471805599453f);
#endif
}

__device__ __forceinline__ void gload_lds16(const void* g, void* l) {
  typedef const uint32_t __attribute__((address_space(1)))* gp_t;
  typedef uint32_t __attribute__((address_space(3)))* lp_t;
  __builtin_amdgcn_global_load_lds((gp_t)(uintptr_t)g, (lp_t)(uint32_t)(uintptr_t)l, 16, 0, 0);
}

// ---------------- f32 -> bf16 elementwise ----------------
__global__ void conv_bf16_kernel(const float* __restrict__ in,
                                 unsigned short* __restrict__ out, int n4) {
  int i = blockIdx.x * blockDim.x + threadIdx.x;
  if (i >= n4) return;
  float4 v = ((const float4*)in)[i];
  ushort4 o;
  o.x = f2bf(v.x); o.y = f2bf(v.y); o.z = f2bf(v.z); o.w = f2bf(v.w);
  ((ushort4*)out)[i] = o;
}

// ---------------- transpose f32 [R][C] -> bf16 [C][R] ----------------
__global__ void transpose_bf16_kernel(const float* __restrict__ W,
                                      unsigned short* __restrict__ WT, int R, int C) {
  __shared__ unsigned short tile[64][65];
  const int c0 = blockIdx.x * 64, r0 = blockIdx.y * 64;
  const int t = threadIdx.x;
  #pragma unroll
  for (int i = 0; i < 16; i++) {
    int idx = i * 256 + t;
    int r = idx >> 6, c = idx & 63;
    tile[r][c] = f2bf(W[(size_t)(r0 + r) * C + c0 + c]);
  }
  __syncthreads();
  #pragma unroll
  for (int i = 0; i < 16; i++) {
    int idx = i * 256 + t;
    int c = idx >> 6, r = idx & 63;
    WT[(size_t)(c0 + c) * R + r0 + r] = tile[r][c];
  }
}

// ---------------- GEMM: A[M][K] bf16 x Bt[N][K] bf16 -> epilogue ----------------
// MODE 0: qkv projection. out scatters to q[BH][T][64] (x0.125*log2e), k[BH][T][64], vT[BH][64][T], bias added.
// MODE 1: proj. c_out[M][N] fp32 = A@B + bias.
template <int MODE>
__global__ void gemm_bt_kernel(const unsigned short* __restrict__ A,
                               const unsigned short* __restrict__ Bt,
                               const float* __restrict__ bias,
                               unsigned short* __restrict__ q_out,
                               unsigned short* __restrict__ k_out,
                               unsigned short* __restrict__ v_out,
                               float* __restrict__ c_out,
                               int K, int N) {
  const int t = threadIdx.x;
  const int w = t >> 6, l = t & 63;
  const int lr = l & 15, lg = l >> 4;
  const int wr = w >> 1, wc = w & 1;
  const int m0 = blockIdx.y * 128, n0 = blockIdx.x * 128;

  __shared__ __align__(16) unsigned short As[128 * 64];
  __shared__ __align__(16) unsigned short Bs[128 * 64];

  f32x4_t acc[4][4];
  #pragma unroll
  for (int mi = 0; mi < 4; mi++)
    #pragma unroll
    for (int ni = 0; ni < 4; ni++)
      acc[mi][ni] = (f32x4_t){0.f, 0.f, 0.f, 0.f};

  const int srow = t >> 3;          // 0..31
  const int scol = (t & 7) * 8;     // element col (16B chunks)
  const size_t abase = (size_t)(m0 + srow) * K + scol;
  const size_t bbase = (size_t)(n0 + srow) * K + scol;

  for (int k0 = 0; k0 < K; k0 += 64) {
    __syncthreads();
    #pragma unroll
    for (int i = 0; i < 4; i++) {
      gload_lds16(A + abase + (size_t)i * 32 * K + k0, &As[(i * 32 + srow) * 64 + scol]);
      gload_lds16(Bt + bbase + (size_t)i * 32 * K + k0, &Bs[(i * 32 + srow) * 64 + scol]);
    }
    __syncthreads();
    #pragma unroll
    for (int ks = 0; ks < 2; ks++) {
      bf16x8_t af[4], bfr[4];
      #pragma unroll
      for (int mi = 0; mi < 4; mi++)
        af[mi] = *(const bf16x8_t*)&As[(wr * 64 + mi * 16 + lr) * 64 + ks * 32 + lg * 8];
      #pragma unroll
      for (int ni = 0; ni < 4; ni++)
        bfr[ni] = *(const bf16x8_t*)&Bs[(wc * 64 + ni * 16 + lr) * 64 + ks * 32 + lg * 8];
      #pragma unroll
      for (int mi = 0; mi < 4; mi++)
        #pragma unroll
        for (int ni = 0; ni < 4; ni++)
          acc[mi][ni] = __builtin_amdgcn_mfma_f32_16x16x32_bf16(af[mi], bfr[ni], acc[mi][ni], 0, 0, 0);
    }
  }

  if (MODE == 0) {
    const float QSCALE = 0.125f * 1.4426950408889634f;  // 1/sqrt(64) * log2(e)
    #pragma unroll
    for (int ni = 0; ni < 4; ni++) {
      const int n = n0 + wc * 64 + ni * 16 + lr;
      const float bv = bias[n];
      const int s = n >> 10;           // 0:q 1:k 2:v
      const int hh = (n >> 6) & 15;    // head
      const int d = n & 63;            // dim in head
      #pragma unroll
      for (int mi = 0; mi < 4; mi++) {
        const int mbase = m0 + wr * 64 + mi * 16 + lg * 4;
        const int batch = mbase >> 11;
        const int tt = mbase & 2047;
        const int bhh = batch * NHEAD + hh;
        if (s == 0) {
          #pragma unroll
          for (int r = 0; r < 4; r++)
            q_out[((size_t)bhh * T_SEQ + tt + r) * 64 + d] = f2bf((acc[mi][ni][r] + bv) * QSCALE);
        } else if (s == 1) {
          #pragma unroll
          for (int r = 0; r < 4; r++)
            k_out[((size_t)bhh * T_SEQ + tt + r) * 64 + d] = f2bf(acc[mi][ni][r] + bv);
        } else {
          ushort4 pk;
          pk.x = f2bf(acc[mi][ni][0] + bv);
          pk.y = f2bf(acc[mi][ni][1] + bv);
          pk.z = f2bf(acc[mi][ni][2] + bv);
          pk.w = f2bf(acc[mi][ni][3] + bv);
          *(ushort4*)&v_out[((size_t)bhh * 64 + d) * T_SEQ + tt] = pk;
        }
      }
    }
  } else {
    #pragma unroll
    for (int ni = 0; ni < 4; ni++) {
      const int n = n0 + wc * 64 + ni * 16 + lr;
      const float bv = bias[n];
      #pragma unroll
      for (int mi = 0; mi < 4; mi++) {
        const int m = m0 + wr * 64 + mi * 16 + lg * 4;
        #pragma unroll
        for (int r = 0; r < 4; r++)
          c_out[(size_t)(m + r) * N + n] = acc[mi][ni][r] + bv;
      }
    }
  }
}

// ---------------- causal flash attention, barrier-free kv loop ----------------
// Q[BH][T][64] bf16 (pre-scaled by 0.125*log2e), K[BH][T][64] bf16, Vt[BH][64][T] bf16
// O[B][T][C] bf16 (attention output, pre-projection)
// Block = 128 threads (2 waves). Both waves own the SAME 32 q-rows (one strip);
// kv tiles are split even/odd between the waves (split-K), online-softmax
// states merged at the end through LDS. No __syncthreads in the kv loop;
// K/V fragments read directly from global (L2-resident: 256KB/head).
__global__ __launch_bounds__(128, 4)
void attn_kernel(const unsigned short* __restrict__ Qb,
                 const unsigned short* __restrict__ Kb,
                 const unsigned short* __restrict__ Vt,
                 unsigned short* __restrict__ O) {
  const int strip = 63 - blockIdx.x;      // heavy strips dispatch first
  const int bh = blockIdx.y;
  const int batch = bh >> 4, h = bh & 15;
  const int q0 = strip * 32;
  const int t = threadIdx.x;
  const int w = t >> 6, l = t & 63;
  const int lr = l & 15, lg = l >> 4;

  // union: per-wave P staging (2 x 32x72 bf16 = 9216B) / combine buffer (64 x 49 f32 = 12544B)
  __shared__ __align__(16) unsigned char smem[12544];
  unsigned short* Ps = (unsigned short*)smem;
  float* comb = (float*)smem;

  const size_t kvbase = (size_t)bh * T_SEQ;

  // Q fragments held in registers for whole loop (both waves: same rows)
  bf16x8_t qf[2][2];
  #pragma unroll
  for (int mi = 0; mi < 2; mi++)
    #pragma unroll
    for (int ks = 0; ks < 2; ks++)
      qf[mi][ks] = *(const bf16x8_t*)&Qb[(kvbase + q0 + mi * 16 + lr) * 64 + ks * 32 + lg * 8];

  f32x4_t acc_o[2][4];
  float m_run[2][4], l_run[2][4];
  #pragma unroll
  for (int mi = 0; mi < 2; mi++) {
    #pragma unroll
    for (int di = 0; di < 4; di++) acc_o[mi][di] = (f32x4_t){0.f, 0.f, 0.f, 0.f};
    #pragma unroll
    for (int r = 0; r < 4; r++) { m_run[mi][r] = -1e30f; l_run[mi][r] = 0.f; }
  }

  const int nt = strip / 2 + 1;                 // kv tiles for this strip
  unsigned short* myPs = Ps + w * (32 * 72);

  for (int ti = w; ti < nt; ti += 2) {
    const int kv0 = ti * 64;
    // ---- S = Q K^T (K fragments straight from global) ----
    f32x4_t sc4[2][4];
    #pragma unroll
    for (int mi = 0; mi < 2; mi++)
      #pragma unroll
      for (int ni = 0; ni < 4; ni++)
        sc4[mi][ni] = (f32x4_t){0.f, 0.f, 0.f, 0.f};
    #pragma unroll
    for (int ks = 0; ks < 2; ks++) {
      bf16x8_t bk[4];
      #pragma unroll
      for (int ni = 0; ni < 4; ni++)
        bk[ni] = *(const bf16x8_t*)&Kb[(kvbase + kv0 + ni * 16 + lr) * 64 + ks * 32 + lg * 8];
      #pragma unroll
      for (int mi = 0; mi < 2; mi++)
        #pragma unroll
        for (int ni = 0; ni < 4; ni++)
          sc4[mi][ni] = __builtin_amdgcn_mfma_f32_16x16x32_bf16(qf[mi][ks], bk[ni], sc4[mi][ni], 0, 0, 0);
    }
    // ---- causal mask (only the diagonal-straddling tile needs it) ----
    if (kv0 + 63 > q0) {
      #pragma unroll
      for (int mi = 0; mi < 2; mi++)
        #pragma unroll
        for (int ni = 0; ni < 4; ni++)
          #pragma unroll
          for (int r = 0; r < 4; r++)
            if (kv0 + ni * 16 + lr > q0 + mi * 16 + lg * 4 + r) sc4[mi][ni][r] = -1e30f;
    }
    // ---- online softmax (base-2) ----
    #pragma unroll
    for (int mi = 0; mi < 2; mi++) {
      float mx[4], ps[4], nm[4], scal[4];
      #pragma unroll
      for (int r = 0; r < 4; r++)
        mx[r] = fmaxf(fmaxf(sc4[mi][0][r], sc4[mi][1][r]), fmaxf(sc4[mi][2][r], sc4[mi][3][r]));
      #pragma unroll
      for (int off = 8; off >= 1; off >>= 1)
        #pragma unroll
        for (int r = 0; r < 4; r++)
          mx[r] = fmaxf(mx[r], __shfl_xor(mx[r], off, 64));
      #pragma unroll
      for (int r = 0; r < 4; r++) {
        nm[r] = fmaxf(m_run[mi][r], mx[r]);
        scal[r] = fast_exp2(m_run[mi][r] - nm[r]);
        m_run[mi][r] = nm[r];
        ps[r] = 0.f;
      }
      #pragma unroll
      for (int ni = 0; ni < 4; ni++)
        #pragma unroll
        for (int r = 0; r < 4; r++) {
          float p = fast_exp2(sc4[mi][ni][r] - nm[r]);
          sc4[mi][ni][r] = p;
          ps[r] += p;
        }
      #pragma unroll
      for (int off = 8; off >= 1; off >>= 1)
        #pragma unroll
        for (int r = 0; r < 4; r++)
          ps[r] += __shfl_xor(ps[r], off, 64);
      #pragma unroll
      for (int r = 0; r < 4; r++)
        l_run[mi][r] = l_run[mi][r] * scal[r] + ps[r];
      #pragma unroll
      for (int di = 0; di < 4; di++)
        #pragma unroll
        for (int r = 0; r < 4; r++)
          acc_o[mi][di][r] *= scal[r];
      // P -> per-wave LDS (A-fragment layout source)
      #pragma unroll
      for (int ni = 0; ni < 4; ni++)
        #pragma unroll
        for (int r = 0; r < 4; r++)
          myPs[(mi * 16 + lg * 4 + r) * 72 + ni * 16 + lr] = f2bf(sc4[mi][ni][r]);
    }
    asm volatile("s_waitcnt lgkmcnt(0)" ::: "memory");
    // ---- O += P V (V fragments straight from global, transposed layout) ----
    #pragma unroll
    for (int ks = 0; ks < 2; ks++) {
      bf16x8_t pa[2], bv[4];
      #pragma unroll
      for (int mi = 0; mi < 2; mi++)
        pa[mi] = *(const bf16x8_t*)&myPs[(mi * 16 + lr) * 72 + ks * 32 + lg * 8];
      #pragma unroll
      for (int di = 0; di < 4; di++)
        bv[di] = *(const bf16x8_t*)&Vt[((size_t)bh * 64 + di * 16 + lr) * T_SEQ + kv0 + ks * 32 + lg * 8];
      #pragma unroll
      for (int mi = 0; mi < 2; mi++)
        #pragma unroll
        for (int di = 0; di < 4; di++)
          acc_o[mi][di] = __builtin_amdgcn_mfma_f32_16x16x32_bf16(pa[mi], bv[di], acc_o[mi][di], 0, 0, 0);
    }
  }

  // ---- merge the two waves' online-softmax states ----
  __syncthreads();                    // both waves done with loop (Ps dead after this)
  float* cb = comb + l * 49;
  if (w == 1) {
    #pragma unroll
    for (int mi = 0; mi < 2; mi++)
      #pragma unroll
      for (int r = 0; r < 4; r++) {
        cb[mi * 4 + r] = m_run[mi][r];
        cb[8 + mi * 4 + r] = l_run[mi][r];
      }
    #pragma unroll
    for (int mi = 0; mi < 2; mi++)
      #pragma unroll
      for (int di = 0; di < 4; di++)
        #pragma unroll
        for (int r = 0; r < 4; r++)
          cb[16 + (mi * 4 + di) * 4 + r] = acc_o[mi][di][r];
  }
  __syncthreads();
  if (w == 0) {
    #pragma unroll
    for (int mi = 0; mi < 2; mi++)
      #pragma unroll
      for (int r = 0; r < 4; r++) {
        const float m1 = cb[mi * 4 + r], l1 = cb[8 + mi * 4 + r];
        const float mm = fmaxf(m_run[mi][r], m1);
        const float s0 = fast_exp2(m_run[mi][r] - mm);
        const float s1 = fast_exp2(m1 - mm);
        const float rl = 1.f / (l_run[mi][r] * s0 + l1 * s1);
        const int tt = q0 + mi * 16 + lg * 4 + r;
        #pragma unroll
        for (int di = 0; di < 4; di++) {
          const float vv = (acc_o[mi][di][r] * s0 + cb[16 + (mi * 4 + di) * 4 + r] * s1) * rl;
          O[((size_t)batch * T_SEQ + tt) * CDIM + h * 64 + di * 16 + lr] = f2bf(vv);
        }
      }
  }
}

extern "C" void kernel_launch(void* const* d_in, const int* in_sizes, int n_in,
                              void* d_out, int out_size, void* d_ws, size_t ws_size,
                              hipStream_t stream) {
  (void)in_sizes; (void)n_in; (void)out_size; (void)ws_size;
  const float* x      = (const float*)d_in[0];
  const float* w_qkv  = (const float*)d_in[1];
  const float* b_qkv  = (const float*)d_in[2];
  const float* w_proj = (const float*)d_in[3];
  const float* b_proj = (const float*)d_in[4];
  float* out = (float*)d_out;

  char* ws = (char*)d_ws;
  unsigned short* xb     = (unsigned short*)(ws);                       // 8 MB  x bf16 [4096][1024]
  unsigned short* wqkvT  = (unsigned short*)(ws + ((size_t)8  << 20));  // 6 MB  [3072][1024]
  unsigned short* wprojT = (unsigned short*)(ws + ((size_t)14 << 20));  // 2 MB  [1024][1024]
  unsigned short* qb     = (unsigned short*)(ws + ((size_t)16 << 20));  // 8 MB  [32][2048][64]
  unsigned short* kb     = (unsigned short*)(ws + ((size_t)24 << 20));  // 8 MB  [32][2048][64]
  unsigned short* vtb    = (unsigned short*)(ws + ((size_t)32 << 20));  // 8 MB  [32][64][2048]
  unsigned short* ab     = (unsigned short*)(ws + ((size_t)40 << 20));  // 8 MB  attn out [4096][1024]

  conv_bf16_kernel<<<4096, 256, 0, stream>>>(x, xb, (2 * T_SEQ * CDIM) / 4);
  transpose_bf16_kernel<<<dim3(48, 16), 256, 0, stream>>>(w_qkv, wqkvT, 1024, 3072);
  transpose_bf16_kernel<<<dim3(16, 16), 256, 0, stream>>>(w_proj, wprojT, 1024, 1024);
  gemm_bt_kernel<0><<<dim3(24, 32), 256, 0, stream>>>(xb, wqkvT, b_qkv, qb, kb, vtb, nullptr, 1024, 3072);
  attn_kernel<<<dim3(64, 32), 128, 0, stream>>>(qb, kb, vtb, ab);
  gemm_bt_kernel<1><<<dim3(8, 32), 256, 0, stream>>>(ab, wprojT, b_proj, nullptr, nullptr, nullptr, out, 1024, 1024);
}

// Round 3
// 179.868 us; speedup vs baseline: 1.4102x; 1.4102x over previous
//
#include <hip/hip_runtime.h>
#include <cstdint>

typedef __attribute__((ext_vector_type(8))) short bf16x8_t;
typedef __attribute__((ext_vector_type(4))) float f32x4_t;

#define T_SEQ 2048
#define NHEAD 16
#define CDIM  1024

__device__ __forceinline__ unsigned short f2bf(float f) {
  union { float f; unsigned u; } v; v.f = f;
  unsigned r = v.u + 0x7FFFu + ((v.u >> 16) & 1u);
  return (unsigned short)(r >> 16);
}

__device__ __forceinline__ float fast_exp2(float x) {
#if __has_builtin(__builtin_amdgcn_exp2f)
  return __builtin_amdgcn_exp2f(x);
#else
  return __expf(x * 0.6931471805599453f);
#endif
}

__device__ __forceinline__ void gload_lds16(const void* g, void* l) {
  typedef const uint32_t __attribute__((address_space(1)))* gp_t;
  typedef uint32_t __attribute__((address_space(3)))* lp_t;
  __builtin_amdgcn_global_load_lds((gp_t)(uintptr_t)g, (lp_t)(uint32_t)(uintptr_t)l, 16, 0, 0);
}

// ---------------- f32 -> bf16 elementwise ----------------
__global__ void conv_bf16_kernel(const float* __restrict__ in,
                                 unsigned short* __restrict__ out, int n4) {
  int i = blockIdx.x * blockDim.x + threadIdx.x;
  if (i >= n4) return;
  float4 v = ((const float4*)in)[i];
  ushort4 o;
  o.x = f2bf(v.x); o.y = f2bf(v.y); o.z = f2bf(v.z); o.w = f2bf(v.w);
  ((ushort4*)out)[i] = o;
}

// ---------------- transpose f32 [R][C] -> bf16 [C][R] ----------------
__global__ void transpose_bf16_kernel(const float* __restrict__ W,
                                      unsigned short* __restrict__ WT, int R, int C) {
  __shared__ unsigned short tile[64][65];
  const int c0 = blockIdx.x * 64, r0 = blockIdx.y * 64;
  const int t = threadIdx.x;
  #pragma unroll
  for (int i = 0; i < 16; i++) {
    int idx = i * 256 + t;
    int r = idx >> 6, c = idx & 63;
    tile[r][c] = f2bf(W[(size_t)(r0 + r) * C + c0 + c]);
  }
  __syncthreads();
  #pragma unroll
  for (int i = 0; i < 16; i++) {
    int idx = i * 256 + t;
    int c = idx >> 6, r = idx & 63;
    WT[(size_t)(c0 + c) * R + r0 + r] = tile[r][c];
  }
}

// ---------------- GEMM: A[M][K] bf16 x Bt[N][K] bf16 -> epilogue ----------------
// MODE 0: qkv projection. Scatters:
//   q[BH][T][64]  (x 0.125*log2e)               -- unswizzled
//   k[BH][T][64]  with 16B-chunk XOR swizzle: chunk ^= (row&7)   (row = kv pos)
//   vT[BH][64][T] with 16B-chunk XOR swizzle within each 64-col tile: chunk ^= (d&7)
// MODE 1: proj. c_out[M][N] fp32 = A@B + bias.
template <int MODE>
__global__ void gemm_bt_kernel(const unsigned short* __restrict__ A,
                               const unsigned short* __restrict__ Bt,
                               const float* __restrict__ bias,
                               unsigned short* __restrict__ q_out,
                               unsigned short* __restrict__ k_out,
                               unsigned short* __restrict__ v_out,
                               float* __restrict__ c_out,
                               int K, int N) {
  const int t = threadIdx.x;
  const int w = t >> 6, l = t & 63;
  const int lr = l & 15, lg = l >> 4;
  const int wr = w >> 1, wc = w & 1;
  const int m0 = blockIdx.y * 128, n0 = blockIdx.x * 128;

  __shared__ __align__(16) unsigned short As[128 * 64];
  __shared__ __align__(16) unsigned short Bs[128 * 64];

  f32x4_t acc[4][4];
  #pragma unroll
  for (int mi = 0; mi < 4; mi++)
    #pragma unroll
    for (int ni = 0; ni < 4; ni++)
      acc[mi][ni] = (f32x4_t){0.f, 0.f, 0.f, 0.f};

  const int srow = t >> 3;          // 0..31
  const int scol = (t & 7) * 8;     // element col (16B chunks)
  const size_t abase = (size_t)(m0 + srow) * K + scol;
  const size_t bbase = (size_t)(n0 + srow) * K + scol;

  for (int k0 = 0; k0 < K; k0 += 64) {
    __syncthreads();
    #pragma unroll
    for (int i = 0; i < 4; i++) {
      gload_lds16(A + abase + (size_t)i * 32 * K + k0, &As[(i * 32 + srow) * 64 + scol]);
      gload_lds16(Bt + bbase + (size_t)i * 32 * K + k0, &Bs[(i * 32 + srow) * 64 + scol]);
    }
    __syncthreads();
    #pragma unroll
    for (int ks = 0; ks < 2; ks++) {
      bf16x8_t af[4], bfr[4];
      #pragma unroll
      for (int mi = 0; mi < 4; mi++)
        af[mi] = *(const bf16x8_t*)&As[(wr * 64 + mi * 16 + lr) * 64 + ks * 32 + lg * 8];
      #pragma unroll
      for (int ni = 0; ni < 4; ni++)
        bfr[ni] = *(const bf16x8_t*)&Bs[(wc * 64 + ni * 16 + lr) * 64 + ks * 32 + lg * 8];
      #pragma unroll
      for (int mi = 0; mi < 4; mi++)
        #pragma unroll
        for (int ni = 0; ni < 4; ni++)
          acc[mi][ni] = __builtin_amdgcn_mfma_f32_16x16x32_bf16(af[mi], bfr[ni], acc[mi][ni], 0, 0, 0);
    }
  }

  if (MODE == 0) {
    const float QSCALE = 0.125f * 1.4426950408889634f;  // 1/sqrt(64) * log2(e)
    #pragma unroll
    for (int ni = 0; ni < 4; ni++) {
      const int n = n0 + wc * 64 + ni * 16 + lr;
      const float bv = bias[n];
      const int s = n >> 10;           // 0:q 1:k 2:v
      const int hh = (n >> 6) & 15;    // head
      const int d = n & 63;            // dim in head
      #pragma unroll
      for (int mi = 0; mi < 4; mi++) {
        const int mbase = m0 + wr * 64 + mi * 16 + lg * 4;
        const int batch = mbase >> 11;
        const int tt = mbase & 2047;
        const int bhh = batch * NHEAD + hh;
        if (s == 0) {
          #pragma unroll
          for (int r = 0; r < 4; r++)
            q_out[((size_t)bhh * T_SEQ + tt + r) * 64 + d] = f2bf((acc[mi][ni][r] + bv) * QSCALE);
        } else if (s == 1) {
          #pragma unroll
          for (int r = 0; r < 4; r++) {
            const int dsw = ((((d >> 3) ^ ((tt + r) & 7)) << 3) | (d & 7));
            k_out[((size_t)bhh * T_SEQ + tt + r) * 64 + dsw] = f2bf(acc[mi][ni][r] + bv);
          }
        } else {
          ushort4 pk;
          pk.x = f2bf(acc[mi][ni][0] + bv);
          pk.y = f2bf(acc[mi][ni][1] + bv);
          pk.z = f2bf(acc[mi][ni][2] + bv);
          pk.w = f2bf(acc[mi][ni][3] + bv);
          const int c2 = (((tt >> 3) & 7) ^ (d & 7));
          const int tt2 = (tt & ~63) | (c2 << 3) | (tt & 7);
          *(ushort4*)&v_out[((size_t)bhh * 64 + d) * T_SEQ + tt2] = pk;
        }
      }
    }
  } else {
    #pragma unroll
    for (int ni = 0; ni < 4; ni++) {
      const int n = n0 + wc * 64 + ni * 16 + lr;
      const float bv = bias[n];
      #pragma unroll
      for (int mi = 0; mi < 4; mi++) {
        const int m = m0 + wr * 64 + mi * 16 + lg * 4;
        #pragma unroll
        for (int r = 0; r < 4; r++)
          c_out[(size_t)(m + r) * N + n] = acc[mi][ni][r] + bv;
      }
    }
  }
}

// ---------------- causal flash attention v3 ----------------
// Pair-balanced, double-buffered, swizzled-LDS.
// Block = 128 threads (2 waves). Handles q-strip pair (p, 31-p), 64 rows each;
// every block = exactly 33 kv tiles. Wave w owns rows [q0 + w*32, +32).
// K/V staged via global_load_lds (16B) from pre-swizzled global layout;
// one __syncthreads per tile (its implicit vmcnt(0) drain = prefetch wait).
__global__ __launch_bounds__(128)
void attn_kernel(const unsigned short* __restrict__ Qb,
                 const unsigned short* __restrict__ Kswz,
                 const unsigned short* __restrict__ Vswz,
                 unsigned short* __restrict__ O) {
  // bijective XCD swizzle over 512 blocks: each XCD gets 64 contiguous wg = 4 heads
  const int b0 = blockIdx.x;
  const int wg = (b0 & 7) * 64 + (b0 >> 3);
  const int bh = wg >> 4;          // 0..31
  const int p  = wg & 15;          // pair 0..15
  const int batch = bh >> 4, h = bh & 15;
  const int q0A = p * 64;
  const int q0B = (31 - p) * 64;
  const int nA = p + 1;            // tiles for strip A
  const int NT = 33;               // nA + (32 - p)

  const int t = threadIdx.x;
  const int w = t >> 6, l = t & 63;
  const int lr = l & 15, lg = l >> 4;

  __shared__ __align__(16) unsigned short Ks[2][64 * 64];
  __shared__ __align__(16) unsigned short Vs[2][64 * 64];
  __shared__ __align__(16) unsigned short Ps[2][32 * 72];

  const size_t kvbase = (size_t)bh * T_SEQ;
  unsigned short* myPs = Ps[w];

  // ---- staging: 8 x global_load_lds(16B) per thread per tile ----
  auto stage = [&](int buf, int kv0) {
    #pragma unroll
    for (int i = 0; i < 4; i++) {
      const int row0 = w * 32 + i * 8;
      gload_lds16(Kswz + (kvbase + kv0 + row0 + (l >> 3)) * 64 + (l & 7) * 8,
                  &Ks[buf][row0 * 64 + l * 8]);
    }
    #pragma unroll
    for (int i = 0; i < 4; i++) {
      const int row0 = w * 32 + i * 8;
      gload_lds16(Vswz + ((size_t)bh * 64 + row0 + (l >> 3)) * T_SEQ + kv0 + (l & 7) * 8,
                  &Vs[buf][row0 * 64 + l * 8]);
    }
  };

  bf16x8_t qf[2][2];
  auto load_q = [&](int q0) {
    #pragma unroll
    for (int mi = 0; mi < 2; mi++)
      #pragma unroll
      for (int ks = 0; ks < 2; ks++)
        qf[mi][ks] = *(const bf16x8_t*)&Qb[(kvbase + q0 + w * 32 + mi * 16 + lr) * 64 + ks * 32 + lg * 8];
  };

  f32x4_t acc_o[2][4];
  float m_run[2][4], l_run[2][4];
  auto reset_state = [&]() {
    #pragma unroll
    for (int mi = 0; mi < 2; mi++) {
      #pragma unroll
      for (int di = 0; di < 4; di++) acc_o[mi][di] = (f32x4_t){0.f, 0.f, 0.f, 0.f};
      #pragma unroll
      for (int r = 0; r < 4; r++) { m_run[mi][r] = -1e30f; l_run[mi][r] = 0.f; }
    }
  };
  auto store_o = [&](int q0) {
    #pragma unroll
    for (int mi = 0; mi < 2; mi++)
      #pragma unroll
      for (int r = 0; r < 4; r++) {
        const float rl = 1.0f / l_run[mi][r];
        const int tt = q0 + w * 32 + mi * 16 + lg * 4 + r;
        #pragma unroll
        for (int di = 0; di < 4; di++)
          O[((size_t)batch * T_SEQ + tt) * CDIM + h * 64 + di * 16 + lr] =
              f2bf(acc_o[mi][di][r] * rl);
      }
  };

  load_q(q0A);
  reset_state();
  stage(0, 0);
  __syncthreads();
  int cur = 0;

  for (int idx = 0; idx < NT; ++idx) {
    const int phase = (idx >= nA) ? 1 : 0;
    const int ti = phase ? idx - nA : idx;
    const int q0 = phase ? q0B : q0A;
    const int kv0 = ti * 64;

    // prefetch next tile into the other buffer
    if (idx + 1 < NT) {
      const int nti = (idx + 1 >= nA) ? (idx + 1 - nA) : (idx + 1);
      stage(cur ^ 1, nti * 64);
    }

    // ---- QK^T from swizzled LDS ----
    f32x4_t sc4[2][4];
    #pragma unroll
    for (int mi = 0; mi < 2; mi++)
      #pragma unroll
      for (int ni = 0; ni < 4; ni++)
        sc4[mi][ni] = (f32x4_t){0.f, 0.f, 0.f, 0.f};
    #pragma unroll
    for (int ks = 0; ks < 2; ks++) {
      bf16x8_t bk[4];
      #pragma unroll
      for (int ni = 0; ni < 4; ni++) {
        const int row = ni * 16 + lr;
        bk[ni] = *(const bf16x8_t*)&Ks[cur][row * 64 + (((ks * 4 + lg) ^ (row & 7)) << 3)];
      }
      #pragma unroll
      for (int mi = 0; mi < 2; mi++)
        #pragma unroll
        for (int ni = 0; ni < 4; ni++)
          sc4[mi][ni] = __builtin_amdgcn_mfma_f32_16x16x32_bf16(qf[mi][ks], bk[ni], sc4[mi][ni], 0, 0, 0);
    }

    // ---- causal mask (diagonal tile only) ----
    if (kv0 == q0) {
      #pragma unroll
      for (int mi = 0; mi < 2; mi++)
        #pragma unroll
        for (int ni = 0; ni < 4; ni++)
          #pragma unroll
          for (int r = 0; r < 4; r++)
            if (ni * 16 + lr > w * 32 + mi * 16 + lg * 4 + r) sc4[mi][ni][r] = -1e30f;
    }

    // ---- online softmax (base-2) ----
    #pragma unroll
    for (int mi = 0; mi < 2; mi++) {
      float mx[4], ps[4], nm[4], scal[4];
      #pragma unroll
      for (int r = 0; r < 4; r++)
        mx[r] = fmaxf(fmaxf(sc4[mi][0][r], sc4[mi][1][r]), fmaxf(sc4[mi][2][r], sc4[mi][3][r]));
      #pragma unroll
      for (int off = 8; off >= 1; off >>= 1)
        #pragma unroll
        for (int r = 0; r < 4; r++)
          mx[r] = fmaxf(mx[r], __shfl_xor(mx[r], off, 64));
      #pragma unroll
      for (int r = 0; r < 4; r++) {
        nm[r] = fmaxf(m_run[mi][r], mx[r]);
        scal[r] = fast_exp2(m_run[mi][r] - nm[r]);
        m_run[mi][r] = nm[r];
        ps[r] = 0.f;
      }
      #pragma unroll
      for (int ni = 0; ni < 4; ni++)
        #pragma unroll
        for (int r = 0; r < 4; r++) {
          float pv = fast_exp2(sc4[mi][ni][r] - nm[r]);
          sc4[mi][ni][r] = pv;
          ps[r] += pv;
        }
      #pragma unroll
      for (int off = 8; off >= 1; off >>= 1)
        #pragma unroll
        for (int r = 0; r < 4; r++)
          ps[r] += __shfl_xor(ps[r], off, 64);
      #pragma unroll
      for (int r = 0; r < 4; r++)
        l_run[mi][r] = l_run[mi][r] * scal[r] + ps[r];
      #pragma unroll
      for (int di = 0; di < 4; di++)
        #pragma unroll
        for (int r = 0; r < 4; r++)
          acc_o[mi][di][r] *= scal[r];
      #pragma unroll
      for (int ni = 0; ni < 4; ni++)
        #pragma unroll
        for (int r = 0; r < 4; r++)
          myPs[(mi * 16 + lg * 4 + r) * 72 + ni * 16 + lr] = f2bf(sc4[mi][ni][r]);
    }
    asm volatile("s_waitcnt lgkmcnt(0)" ::: "memory");

    // ---- O += P V from swizzled LDS ----
    #pragma unroll
    for (int ks = 0; ks < 2; ks++) {
      bf16x8_t pa[2], bv[4];
      #pragma unroll
      for (int mi = 0; mi < 2; mi++)
        pa[mi] = *(const bf16x8_t*)&myPs[(mi * 16 + lr) * 72 + ks * 32 + lg * 8];
      #pragma unroll
      for (int di = 0; di < 4; di++) {
        const int d = di * 16 + lr;
        bv[di] = *(const bf16x8_t*)&Vs[cur][d * 64 + (((ks * 4 + lg) ^ (d & 7)) << 3)];
      }
      #pragma unroll
      for (int mi = 0; mi < 2; mi++)
        #pragma unroll
        for (int di = 0; di < 4; di++)
          acc_o[mi][di] = __builtin_amdgcn_mfma_f32_16x16x32_bf16(pa[mi], bv[di], acc_o[mi][di], 0, 0, 0);
    }

    __syncthreads();   // implicit vmcnt(0)+lgkmcnt(0) drain: prefetch complete for all waves
    cur ^= 1;

    if (idx == nA - 1) {    // strip A done: flush, switch to strip B
      store_o(q0A);
      load_q(q0B);
      reset_state();
    }
  }
  store_o(q0B);
}

extern "C" void kernel_launch(void* const* d_in, const int* in_sizes, int n_in,
                              void* d_out, int out_size, void* d_ws, size_t ws_size,
                              hipStream_t stream) {
  (void)in_sizes; (void)n_in; (void)out_size; (void)ws_size;
  const float* x      = (const float*)d_in[0];
  const float* w_qkv  = (const float*)d_in[1];
  const float* b_qkv  = (const float*)d_in[2];
  const float* w_proj = (const float*)d_in[3];
  const float* b_proj = (const float*)d_in[4];
  float* out = (float*)d_out;

  char* ws = (char*)d_ws;
  unsigned short* xb     = (unsigned short*)(ws);                       // 8 MB  x bf16 [4096][1024]
  unsigned short* wqkvT  = (unsigned short*)(ws + ((size_t)8  << 20));  // 6 MB  [3072][1024]
  unsigned short* wprojT = (unsigned short*)(ws + ((size_t)14 << 20));  // 2 MB  [1024][1024]
  unsigned short* qb     = (unsigned short*)(ws + ((size_t)16 << 20));  // 8 MB  [32][2048][64]
  unsigned short* kb     = (unsigned short*)(ws + ((size_t)24 << 20));  // 8 MB  [32][2048][64] (swizzled)
  unsigned short* vtb    = (unsigned short*)(ws + ((size_t)32 << 20));  // 8 MB  [32][64][2048] (swizzled)
  unsigned short* ab     = (unsigned short*)(ws + ((size_t)40 << 20));  // 8 MB  attn out [4096][1024]

  conv_bf16_kernel<<<4096, 256, 0, stream>>>(x, xb, (2 * T_SEQ * CDIM) / 4);
  transpose_bf16_kernel<<<dim3(48, 16), 256, 0, stream>>>(w_qkv, wqkvT, 1024, 3072);
  transpose_bf16_kernel<<<dim3(16, 16), 256, 0, stream>>>(w_proj, wprojT, 1024, 1024);
  gemm_bt_kernel<0><<<dim3(24, 32), 256, 0, stream>>>(xb, wqkvT, b_qkv, qb, kb, vtb, nullptr, 1024, 3072);
  attn_kernel<<<512, 128, 0, stream>>>(qb, kb, vtb, ab);
  gemm_bt_kernel<1><<<dim3(8, 32), 256, 0, stream>>>(ab, wprojT, b_proj, nullptr, nullptr, nullptr, out, 1024, 1024);
}

// Round 4
// 174.339 us; speedup vs baseline: 1.4549x; 1.0317x over previous
//
#include <hip/hip_runtime.h>
#include <cstdint>

typedef __attribute__((ext_vector_type(8))) short bf16x8_t;
typedef __attribute__((ext_vector_type(4))) float f32x4_t;

#define T_SEQ 2048
#define NHEAD 16
#define CDIM  1024

__device__ __forceinline__ unsigned short f2bf(float f) {
  union { float f; unsigned u; } v; v.f = f;
  unsigned r = v.u + 0x7FFFu + ((v.u >> 16) & 1u);
  return (unsigned short)(r >> 16);
}

__device__ __forceinline__ float fast_exp2(float x) {
#if __has_builtin(__builtin_amdgcn_exp2f)
  return __builtin_amdgcn_exp2f(x);
#else
  return __expf(x * 0.6931471805599453f);
#endif
}

__device__ __forceinline__ void gload_lds16(const void* g, void* l) {
  typedef const uint32_t __attribute__((address_space(1)))* gp_t;
  typedef uint32_t __attribute__((address_space(3)))* lp_t;
  __builtin_amdgcn_global_load_lds((gp_t)(uintptr_t)g, (lp_t)(uint32_t)(uintptr_t)l, 16, 0, 0);
}

// ---------------- f32 -> bf16 elementwise ----------------
__global__ void conv_bf16_kernel(const float* __restrict__ in,
                                 unsigned short* __restrict__ out, int n4) {
  int i = blockIdx.x * blockDim.x + threadIdx.x;
  if (i >= n4) return;
  float4 v = ((const float4*)in)[i];
  ushort4 o;
  o.x = f2bf(v.x); o.y = f2bf(v.y); o.z = f2bf(v.z); o.w = f2bf(v.w);
  ((ushort4*)out)[i] = o;
}

// ---------------- transpose f32 [R][C] -> bf16 [C][R] ----------------
__global__ void transpose_bf16_kernel(const float* __restrict__ W,
                                      unsigned short* __restrict__ WT, int R, int C) {
  __shared__ unsigned short tile[64][65];
  const int c0 = blockIdx.x * 64, r0 = blockIdx.y * 64;
  const int t = threadIdx.x;
  #pragma unroll
  for (int i = 0; i < 16; i++) {
    int idx = i * 256 + t;
    int r = idx >> 6, c = idx & 63;
    tile[r][c] = f2bf(W[(size_t)(r0 + r) * C + c0 + c]);
  }
  __syncthreads();
  #pragma unroll
  for (int i = 0; i < 16; i++) {
    int idx = i * 256 + t;
    int c = idx >> 6, r = idx & 63;
    WT[(size_t)(c0 + c) * R + r0 + r] = tile[r][c];
  }
}

// ---------------- GEMM: A[M][K] bf16 x Bt[N][K] bf16 -> epilogue ----------------
template <int MODE>
__global__ void gemm_bt_kernel(const unsigned short* __restrict__ A,
                               const unsigned short* __restrict__ Bt,
                               const float* __restrict__ bias,
                               unsigned short* __restrict__ q_out,
                               unsigned short* __restrict__ k_out,
                               unsigned short* __restrict__ v_out,
                               float* __restrict__ c_out,
                               int K, int N) {
  const int t = threadIdx.x;
  const int w = t >> 6, l = t & 63;
  const int lr = l & 15, lg = l >> 4;
  const int wr = w >> 1, wc = w & 1;
  const int m0 = blockIdx.y * 128, n0 = blockIdx.x * 128;

  __shared__ __align__(16) unsigned short As[128 * 64];
  __shared__ __align__(16) unsigned short Bs[128 * 64];

  f32x4_t acc[4][4];
  #pragma unroll
  for (int mi = 0; mi < 4; mi++)
    #pragma unroll
    for (int ni = 0; ni < 4; ni++)
      acc[mi][ni] = (f32x4_t){0.f, 0.f, 0.f, 0.f};

  const int srow = t >> 3;
  const int scol = (t & 7) * 8;
  const size_t abase = (size_t)(m0 + srow) * K + scol;
  const size_t bbase = (size_t)(n0 + srow) * K + scol;

  for (int k0 = 0; k0 < K; k0 += 64) {
    __syncthreads();
    #pragma unroll
    for (int i = 0; i < 4; i++) {
      gload_lds16(A + abase + (size_t)i * 32 * K + k0, &As[(i * 32 + srow) * 64 + scol]);
      gload_lds16(Bt + bbase + (size_t)i * 32 * K + k0, &Bs[(i * 32 + srow) * 64 + scol]);
    }
    __syncthreads();
    #pragma unroll
    for (int ks = 0; ks < 2; ks++) {
      bf16x8_t af[4], bfr[4];
      #pragma unroll
      for (int mi = 0; mi < 4; mi++)
        af[mi] = *(const bf16x8_t*)&As[(wr * 64 + mi * 16 + lr) * 64 + ks * 32 + lg * 8];
      #pragma unroll
      for (int ni = 0; ni < 4; ni++)
        bfr[ni] = *(const bf16x8_t*)&Bs[(wc * 64 + ni * 16 + lr) * 64 + ks * 32 + lg * 8];
      #pragma unroll
      for (int mi = 0; mi < 4; mi++)
        #pragma unroll
        for (int ni = 0; ni < 4; ni++)
          acc[mi][ni] = __builtin_amdgcn_mfma_f32_16x16x32_bf16(af[mi], bfr[ni], acc[mi][ni], 0, 0, 0);
    }
  }

  if (MODE == 0) {
    const float QSCALE = 0.125f * 1.4426950408889634f;  // 1/sqrt(64) * log2(e)
    #pragma unroll
    for (int ni = 0; ni < 4; ni++) {
      const int n = n0 + wc * 64 + ni * 16 + lr;
      const float bv = bias[n];
      const int s = n >> 10;           // 0:q 1:k 2:v
      const int hh = (n >> 6) & 15;
      const int d = n & 63;
      #pragma unroll
      for (int mi = 0; mi < 4; mi++) {
        const int mbase = m0 + wr * 64 + mi * 16 + lg * 4;
        const int batch = mbase >> 11;
        const int tt = mbase & 2047;
        const int bhh = batch * NHEAD + hh;
        if (s == 0) {
          #pragma unroll
          for (int r = 0; r < 4; r++)
            q_out[((size_t)bhh * T_SEQ + tt + r) * 64 + d] = f2bf((acc[mi][ni][r] + bv) * QSCALE);
        } else if (s == 1) {
          #pragma unroll
          for (int r = 0; r < 4; r++) {
            const int dsw = ((((d >> 3) ^ ((tt + r) & 7)) << 3) | (d & 7));
            k_out[((size_t)bhh * T_SEQ + tt + r) * 64 + dsw] = f2bf(acc[mi][ni][r] + bv);
          }
        } else {
          ushort4 pk;
          pk.x = f2bf(acc[mi][ni][0] + bv);
          pk.y = f2bf(acc[mi][ni][1] + bv);
          pk.z = f2bf(acc[mi][ni][2] + bv);
          pk.w = f2bf(acc[mi][ni][3] + bv);
          const int c2 = (((tt >> 3) & 7) ^ (d & 7));
          const int tt2 = (tt & ~63) | (c2 << 3) | (tt & 7);
          *(ushort4*)&v_out[((size_t)bhh * 64 + d) * T_SEQ + tt2] = pk;
        }
      }
    }
  } else {
    #pragma unroll
    for (int ni = 0; ni < 4; ni++) {
      const int n = n0 + wc * 64 + ni * 16 + lr;
      const float bv = bias[n];
      #pragma unroll
      for (int mi = 0; mi < 4; mi++) {
        const int m = m0 + wr * 64 + mi * 16 + lg * 4;
        #pragma unroll
        for (int r = 0; r < 4; r++)
          c_out[(size_t)(m + r) * N + n] = acc[mi][ni][r] + bv;
      }
    }
  }
}

// ---------------- causal flash attention v4 ----------------
// 256 threads = 4 waves: (rh = row-half of 64-row strip) x (kp = kv-tile parity).
// Strip-pair balanced (p, 31-p): 33 tiles/block, ~17 serial tiles per wave.
// Single K/V LDS buffer per parity; next superstep preloaded to REGISTERS at
// top of compute, ds_written after consumer barrier (T14). Parity partials
// merged per row-half through LDS (exact fp32 online-softmax merge).
__global__ __launch_bounds__(256, 2)
void attn_kernel(const unsigned short* __restrict__ Qb,
                 const unsigned short* __restrict__ Kswz,
                 const unsigned short* __restrict__ Vswz,
                 unsigned short* __restrict__ O) {
  const int b0 = blockIdx.x;
  const int wg = (b0 & 7) * 64 + (b0 >> 3);     // bijective XCD swizzle
  const int bh = wg >> 4;
  const int p  = wg & 15;
  const int batch = bh >> 4, h = bh & 15;
  const int q0A = p * 64;
  const int q0B = (31 - p) * 64;
  const int nA = p + 1;
  const int NT = 33;

  const int t = threadIdx.x;
  const int w = t >> 6, l = t & 63;
  const int lr = l & 15, lg = l >> 4;
  const int rh = w & 1, kpar = w >> 1;

  __shared__ __align__(16) unsigned short Ks[2][64 * 64];
  __shared__ __align__(16) unsigned short Vs[2][64 * 64];
  __shared__ __align__(16) unsigned short Ps[4][32 * 72];
  __shared__ __align__(16) float comb[2][64][48];

  const size_t kvbase = (size_t)bh * T_SEQ;
  unsigned short* myPs = Ps[w];

  // per-thread staging source pointers (2 x 16B chunks per segment)
  const int flat0 = t, flat1 = 256 + t;
  const int row0 = flat0 >> 3, ch0 = (flat0 & 7) * 8;
  const int row1 = flat1 >> 3, ch1 = (flat1 & 7) * 8;
  const unsigned short* kSrc0 = Kswz + (kvbase + row0) * 64 + ch0;
  const unsigned short* kSrc1 = Kswz + (kvbase + row1) * 64 + ch1;
  const unsigned short* vSrc0 = Vswz + ((size_t)bh * 64 + row0) * T_SEQ + ch0;
  const unsigned short* vSrc1 = Vswz + ((size_t)bh * 64 + row1) * T_SEQ + ch1;

  uint4 pfk[2][2], pfv[2][2];
  auto issue_pf = [&](int tss) {
    #pragma unroll
    for (int P = 0; P < 2; P++) {
      const int idx = 2 * tss + P;
      if (idx < NT) {
        const int ti = (idx < nA) ? idx : idx - nA;
        const int kv0 = ti * 64;
        pfk[P][0] = *(const uint4*)(kSrc0 + kv0 * 64);
        pfk[P][1] = *(const uint4*)(kSrc1 + kv0 * 64);
        pfv[P][0] = *(const uint4*)(vSrc0 + kv0);
        pfv[P][1] = *(const uint4*)(vSrc1 + kv0);
      }
    }
  };
  auto write_pf = [&](int tss) {
    #pragma unroll
    for (int P = 0; P < 2; P++) {
      const int idx = 2 * tss + P;
      if (idx < NT) {
        *(uint4*)&Ks[P][flat0 * 8] = pfk[P][0];
        *(uint4*)&Ks[P][flat1 * 8] = pfk[P][1];
        *(uint4*)&Vs[P][flat0 * 8] = pfv[P][0];
        *(uint4*)&Vs[P][flat1 * 8] = pfv[P][1];
      }
    }
  };

  bf16x8_t qf[2][2];
  auto load_q = [&](int q0) {
    #pragma unroll
    for (int mi = 0; mi < 2; mi++)
      #pragma unroll
      for (int ks = 0; ks < 2; ks++)
        qf[mi][ks] = *(const bf16x8_t*)&Qb[(kvbase + q0 + rh * 32 + mi * 16 + lr) * 64 + ks * 32 + lg * 8];
  };

  f32x4_t acc_o[2][4];
  float m_run[2][4], l_run[2][4];
  auto reset_state = [&]() {
    #pragma unroll
    for (int mi = 0; mi < 2; mi++) {
      #pragma unroll
      for (int di = 0; di < 4; di++) acc_o[mi][di] = (f32x4_t){0.f, 0.f, 0.f, 0.f};
      #pragma unroll
      for (int r = 0; r < 4; r++) { m_run[mi][r] = -1e30f; l_run[mi][r] = 0.f; }
    }
  };
  auto save_comb = [&]() {
    float* c = comb[rh][l];
    #pragma unroll
    for (int mi = 0; mi < 2; mi++)
      #pragma unroll
      for (int r = 0; r < 4; r++) {
        c[mi * 4 + r] = m_run[mi][r];
        c[8 + mi * 4 + r] = l_run[mi][r];
      }
    #pragma unroll
    for (int mi = 0; mi < 2; mi++)
      #pragma unroll
      for (int di = 0; di < 4; di++)
        #pragma unroll
        for (int r = 0; r < 4; r++)
          c[16 + mi * 16 + di * 4 + r] = acc_o[mi][di][r];
  };
  auto save_comb_empty = [&]() {
    float* c = comb[rh][l];
    #pragma unroll
    for (int j = 0; j < 8; j++)  c[j] = -1e30f;
    #pragma unroll
    for (int j = 8; j < 48; j++) c[j] = 0.f;
  };
  auto merge_store = [&](int q0) {
    const float* c = comb[rh][l];
    #pragma unroll
    for (int mi = 0; mi < 2; mi++)
      #pragma unroll
      for (int r = 0; r < 4; r++) {
        const float m1 = c[mi * 4 + r], l1 = c[8 + mi * 4 + r];
        const float mm = fmaxf(m_run[mi][r], m1);
        const float s0 = fast_exp2(m_run[mi][r] - mm);
        const float s1 = fast_exp2(m1 - mm);
        const float rl = 1.f / (l_run[mi][r] * s0 + l1 * s1);
        const int tt = q0 + rh * 32 + mi * 16 + lg * 4 + r;
        #pragma unroll
        for (int di = 0; di < 4; di++) {
          const float vv = (acc_o[mi][di][r] * s0 + c[16 + mi * 16 + di * 4 + r] * s1) * rl;
          O[((size_t)batch * T_SEQ + tt) * CDIM + h * 64 + di * 16 + lr] = f2bf(vv);
        }
      }
  };

  auto compute_tile = [&](int kv0, int q0) {
    f32x4_t sc4[2][4];
    #pragma unroll
    for (int mi = 0; mi < 2; mi++)
      #pragma unroll
      for (int ni = 0; ni < 4; ni++)
        sc4[mi][ni] = (f32x4_t){0.f, 0.f, 0.f, 0.f};
    #pragma unroll
    for (int ks = 0; ks < 2; ks++) {
      bf16x8_t bk[4];
      #pragma unroll
      for (int ni = 0; ni < 4; ni++) {
        const int row = ni * 16 + lr;
        bk[ni] = *(const bf16x8_t*)&Ks[kpar][row * 64 + (((ks * 4 + lg) ^ (row & 7)) << 3)];
      }
      #pragma unroll
      for (int mi = 0; mi < 2; mi++)
        #pragma unroll
        for (int ni = 0; ni < 4; ni++)
          sc4[mi][ni] = __builtin_amdgcn_mfma_f32_16x16x32_bf16(qf[mi][ks], bk[ni], sc4[mi][ni], 0, 0, 0);
    }
    if (kv0 == q0) {   // diagonal tile
      #pragma unroll
      for (int mi = 0; mi < 2; mi++)
        #pragma unroll
        for (int ni = 0; ni < 4; ni++)
          #pragma unroll
          for (int r = 0; r < 4; r++)
            if (ni * 16 + lr > rh * 32 + mi * 16 + lg * 4 + r) sc4[mi][ni][r] = -1e30f;
    }
    #pragma unroll
    for (int mi = 0; mi < 2; mi++) {
      float mx[4], ps[4];
      #pragma unroll
      for (int r = 0; r < 4; r++)
        mx[r] = fmaxf(fmaxf(sc4[mi][0][r], sc4[mi][1][r]), fmaxf(sc4[mi][2][r], sc4[mi][3][r]));
      #pragma unroll
      for (int off = 8; off >= 1; off >>= 1)
        #pragma unroll
        for (int r = 0; r < 4; r++)
          mx[r] = fmaxf(mx[r], __shfl_xor(mx[r], off, 64));
      // defer-rescale (exact, THR=0): skip when no row's max grew
      int grow = (mx[0] > m_run[mi][0]) | (mx[1] > m_run[mi][1]) |
                 (mx[2] > m_run[mi][2]) | (mx[3] > m_run[mi][3]);
      if (__any(grow)) {
        float scal[4];
        #pragma unroll
        for (int r = 0; r < 4; r++) {
          const float nm = fmaxf(m_run[mi][r], mx[r]);
          scal[r] = fast_exp2(m_run[mi][r] - nm);
          m_run[mi][r] = nm;
          l_run[mi][r] *= scal[r];
        }
        #pragma unroll
        for (int di = 0; di < 4; di++)
          #pragma unroll
          for (int r = 0; r < 4; r++)
            acc_o[mi][di][r] *= scal[r];
      }
      #pragma unroll
      for (int r = 0; r < 4; r++) ps[r] = 0.f;
      #pragma unroll
      for (int ni = 0; ni < 4; ni++)
        #pragma unroll
        for (int r = 0; r < 4; r++) {
          float pv = fast_exp2(sc4[mi][ni][r] - m_run[mi][r]);
          sc4[mi][ni][r] = pv;
          ps[r] += pv;
        }
      #pragma unroll
      for (int off = 8; off >= 1; off >>= 1)
        #pragma unroll
        for (int r = 0; r < 4; r++)
          ps[r] += __shfl_xor(ps[r], off, 64);
      #pragma unroll
      for (int r = 0; r < 4; r++)
        l_run[mi][r] += ps[r];
      #pragma unroll
      for (int ni = 0; ni < 4; ni++)
        #pragma unroll
        for (int r = 0; r < 4; r++)
          myPs[(mi * 16 + lg * 4 + r) * 72 + ni * 16 + lr] = f2bf(sc4[mi][ni][r]);
    }
    asm volatile("s_waitcnt lgkmcnt(0)" ::: "memory");
    #pragma unroll
    for (int ks = 0; ks < 2; ks++) {
      bf16x8_t pa[2], bv[4];
      #pragma unroll
      for (int mi = 0; mi < 2; mi++)
        pa[mi] = *(const bf16x8_t*)&myPs[(mi * 16 + lr) * 72 + ks * 32 + lg * 8];
      #pragma unroll
      for (int di = 0; di < 4; di++) {
        const int d = di * 16 + lr;
        bv[di] = *(const bf16x8_t*)&Vs[kpar][d * 64 + (((ks * 4 + lg) ^ (d & 7)) << 3)];
      }
      #pragma unroll
      for (int mi = 0; mi < 2; mi++)
        #pragma unroll
        for (int di = 0; di < 4; di++)
          acc_o[mi][di] = __builtin_amdgcn_mfma_f32_16x16x32_bf16(pa[mi], bv[di], acc_o[mi][di], 0, 0, 0);
    }
  };

  // ---- prologue ----
  int my_strip = (kpar == 0 || nA >= 2) ? 0 : 1;   // kp1 with nA==1 starts in strip B
  load_q(my_strip ? q0B : q0A);
  reset_state();
  if (kpar == 1 && nA == 1) save_comb_empty();     // no A-tiles for parity 1
  issue_pf(0);
  write_pf(0);                                      // compiler inserts vmcnt waits
  __syncthreads();

  // ---- main loop: 17 supersteps x 2 tiles ----
  for (int ss = 0; ss < 17; ss++) {
    if (ss < 16) issue_pf(ss + 1);                  // prefetch to regs (overlaps compute)
    const int my = 2 * ss + kpar;
    if (my < NT) {
      const int st = (my >= nA) ? 1 : 0;
      const int ti = st ? my - nA : my;
      const int q0 = st ? q0B : q0A;
      if (st != my_strip) {                         // first strip-B tile for this wave
        if (kpar == 0) merge_store(q0A);            // combine parities, store strip A
        reset_state();
        load_q(q0B);
        my_strip = 1;
      }
      compute_tile(ti * 64, q0);
      if (kpar == 1 && st == 0 && my + 2 >= nA) save_comb();   // last A-tile: save partials
    }
    __syncthreads();                                // consumers done with this superstep
    if (ss < 16) write_pf(ss + 1);                  // LDS write of prefetched tiles
    __syncthreads();                                // LDS ready
  }

  // ---- strip B merge ----
  if (kpar == 1) save_comb();
  __syncthreads();
  if (kpar == 0) merge_store(q0B);
}

extern "C" void kernel_launch(void* const* d_in, const int* in_sizes, int n_in,
                              void* d_out, int out_size, void* d_ws, size_t ws_size,
                              hipStream_t stream) {
  (void)in_sizes; (void)n_in; (void)out_size; (void)ws_size;
  const float* x      = (const float*)d_in[0];
  const float* w_qkv  = (const float*)d_in[1];
  const float* b_qkv  = (const float*)d_in[2];
  const float* w_proj = (const float*)d_in[3];
  const float* b_proj = (const float*)d_in[4];
  float* out = (float*)d_out;

  char* ws = (char*)d_ws;
  unsigned short* xb     = (unsigned short*)(ws);                       // 8 MB
  unsigned short* wqkvT  = (unsigned short*)(ws + ((size_t)8  << 20));  // 6 MB
  unsigned short* wprojT = (unsigned short*)(ws + ((size_t)14 << 20));  // 2 MB
  unsigned short* qb     = (unsigned short*)(ws + ((size_t)16 << 20));  // 8 MB
  unsigned short* kb     = (unsigned short*)(ws + ((size_t)24 << 20));  // 8 MB (swizzled)
  unsigned short* vtb    = (unsigned short*)(ws + ((size_t)32 << 20));  // 8 MB (swizzled)
  unsigned short* ab     = (unsigned short*)(ws + ((size_t)40 << 20));  // 8 MB

  conv_bf16_kernel<<<4096, 256, 0, stream>>>(x, xb, (2 * T_SEQ * CDIM) / 4);
  transpose_bf16_kernel<<<dim3(48, 16), 256, 0, stream>>>(w_qkv, wqkvT, 1024, 3072);
  transpose_bf16_kernel<<<dim3(16, 16), 256, 0, stream>>>(w_proj, wprojT, 1024, 1024);
  gemm_bt_kernel<0><<<dim3(24, 32), 256, 0, stream>>>(xb, wqkvT, b_qkv, qb, kb, vtb, nullptr, 1024, 3072);
  attn_kernel<<<512, 256, 0, stream>>>(qb, kb, vtb, ab);
  gemm_bt_kernel<1><<<dim3(8, 32), 256, 0, stream>>>(ab, wprojT, b_proj, nullptr, nullptr, nullptr, out, 1024, 1024);
}